// Round 20
// baseline (369.017 us; speedup 1.0000x reference)
//
#include <hip/hip_runtime.h>
#include <hip/hip_bf16.h>

#define K_N_ATOMS 100000
#define K_N_EDGES 400000
#define K_N_MOLS  4000

typedef __attribute__((ext_vector_type(8))) short bf16x8;
typedef __attribute__((ext_vector_type(4))) float f32x4;

__device__ __forceinline__ unsigned short f2bf(float x) {
  union { __hip_bfloat16 b; unsigned short u; } c;
  c.b = __float2bfloat16(x);
  return c.u;
}

__device__ __forceinline__ float bf2f(unsigned short u) {
  union { float f; unsigned u; } c;
  c.u = ((unsigned)u) << 16;
  return c.f;
}

__device__ __forceinline__ unsigned pk2(float a, float b) {
  union { __hip_bfloat162 h; unsigned u; } c;
  c.h = __float22bfloat162_rn(make_float2(a, b));
  return c.u;
}

__device__ __forceinline__ bf16x8 pack8(float4 x, float4 y) {
  union { bf16x8 v; unsigned u[4]; } r;
  r.u[0] = pk2(x.x, x.y); r.u[1] = pk2(x.z, x.w);
  r.u[2] = pk2(y.x, y.y); r.u[3] = pk2(y.z, y.w);
  return r.v;
}

__device__ __forceinline__ float relu(float x) { return fmaxf(x, 0.f); }

// h1 fragment: relu(F + G) elementwise on bf16x8
__device__ __forceinline__ bf16x8 addrelu8(bf16x8 a, bf16x8 b) {
  union { bf16x8 v; unsigned short s[8]; } ua, ub;
  ua.v = a; ub.v = b;
  union { bf16x8 v; unsigned u[4]; } r;
#pragma unroll
  for (int q = 0; q < 4; ++q) {
    float x0 = relu(bf2f(ua.s[2 * q]) + bf2f(ub.s[2 * q]));
    float x1 = relu(bf2f(ua.s[2 * q + 1]) + bf2f(ub.s[2 * q + 1]));
    r.u[q] = pk2(x0, x1);
  }
  return r.v;
}

// ---- weight prep ----
// per step s, layout in wf + s*40960 (shorts):
//   [0,16384)      wfg: A-frags of W' [64 x 256] (W_top|W_bot of Win), jt 0..15, ks 0..1
//   [16384,32768)  w2:  A-frags of Wh [128 x 128], ((jt*4+ks)*64+ln)*8+i
//   [32768,40960)  w3:  A-frags of Wout [128 x 64]
__global__ void prep_w(const float* __restrict__ Win, const float* __restrict__ Wh,
                       const float* __restrict__ Wout, unsigned short* __restrict__ wf) {
  int s = blockIdx.y;
  int flat = (blockIdx.x * 256 + threadIdx.x) * 4;  // 40960 elems, grid.x = 40
  if (flat < 16384) {
    const float* W = Win + s * 16384;
    unsigned short* dst = wf + s * 40960;
    int k = flat >> 7, j = flat & 127;
    float4 w4 = *(const float4*)(W + flat);
    float wv[4] = {w4.x, w4.y, w4.z, w4.w};
#pragma unroll
    for (int c = 0; c < 4; ++c) {
      int jj = j + c, kk = k;
      if (k >= 64) { kk = k - 64; jj += 128; }
      int jt = jj >> 4, ks = kk >> 5, ln = (jj & 15) + 16 * ((kk >> 3) & 3), i = kk & 7;
      dst[((jt * 2 + ks) * 64 + ln) * 8 + i] = f2bf(wv[c]);
    }
  } else if (flat < 32768) {
    const float* W = Wh + s * 16384;
    unsigned short* dst = wf + s * 40960 + 16384;
    int local = flat - 16384;
    int k = local >> 7, j = local & 127;
    float4 w4 = *(const float4*)(W + local);
    float wv[4] = {w4.x, w4.y, w4.z, w4.w};
    int ks = k >> 5, kr = (k >> 3) & 3, i = k & 7;
#pragma unroll
    for (int c = 0; c < 4; ++c) {
      int jj = j + c;
      int jt = jj >> 4, ln = (jj & 15) + 16 * kr;
      dst[((jt * 4 + ks) * 64 + ln) * 8 + i] = f2bf(wv[c]);
    }
  } else {
    const float* W = Wout + s * 8192;
    unsigned short* dst = wf + s * 40960 + 32768;
    int local = flat - 32768;
    int k = local >> 6, j = local & 63;
    float4 w4 = *(const float4*)(W + local);
    float wv[4] = {w4.x, w4.y, w4.z, w4.w};
    int ks = k >> 5, kr = (k >> 3) & 3, i = k & 7;
#pragma unroll
    for (int c = 0; c < 4; ++c) {
      int jj = j + c;
      int jt = jj >> 4, ln = (jj & 15) + 16 * kr;
      dst[((jt * 4 + ks) * 64 + ln) * 8 + i] = f2bf(wv[c]);
    }
  }
}

// ---- counting sort of edges by src ----
__global__ void k_hist(const int* __restrict__ esrc, int* __restrict__ cnt) {
  int t = blockIdx.x * 256 + threadIdx.x;
  if (t < K_N_EDGES) atomicAdd(&cnt[esrc[t]], 1);
}

__global__ void k_blocksum(const int* __restrict__ cnt, int* __restrict__ partial) {
  __shared__ int red[256];
  int i = blockIdx.x * 256 + threadIdx.x;
  red[threadIdx.x] = (i < K_N_ATOMS) ? cnt[i] : 0;
  __syncthreads();
  for (int off = 128; off; off >>= 1) {
    if (threadIdx.x < off) red[threadIdx.x] += red[threadIdx.x + off];
    __syncthreads();
  }
  if (!threadIdx.x) partial[blockIdx.x] = red[0];
}

__global__ void k_scanpart2(int* __restrict__ partial, int nb) {
  __shared__ int sh[512];
  int tid = threadIdx.x;
  int v = (tid < nb) ? partial[tid] : 0;
  sh[tid] = v;
  __syncthreads();
  for (int off = 1; off < 512; off <<= 1) {
    int t = (tid >= off) ? sh[tid - off] : 0;
    __syncthreads();
    sh[tid] += t;
    __syncthreads();
  }
  if (tid < nb) partial[tid] = sh[tid] - v;  // exclusive prefix
}

// scanfinal + mol_bounds merged (same grid shape)
__global__ void k_scanfinal_bounds(const int* __restrict__ cnt, const int* __restrict__ poffs,
                                   int* __restrict__ start, int* __restrict__ cur,
                                   const int* __restrict__ mol_ids, int* __restrict__ mstart) {
  __shared__ int sh[256];
  int tid = threadIdx.x;
  int i = blockIdx.x * 256 + tid;
  int v = (i < K_N_ATOMS) ? cnt[i] : 0;
  sh[tid] = v;
  __syncthreads();
  for (int off = 1; off < 256; off <<= 1) {
    int t = (tid >= off) ? sh[tid - off] : 0;
    __syncthreads();
    sh[tid] += t;
    __syncthreads();
  }
  int ex = sh[tid] - v + poffs[blockIdx.x];
  if (i < K_N_ATOMS) { start[i] = ex; cur[i] = ex; }
  if (i == K_N_ATOMS - 1) start[K_N_ATOMS] = ex + v;

  if (i < K_N_ATOMS) {
    int id = mol_ids[i];
    int prev = (i == 0) ? -1 : mol_ids[i - 1];
    for (int m = prev + 1; m <= id; ++m) mstart[m] = i;
    if (i == K_N_ATOMS - 1)
      for (int m = id + 1; m <= K_N_MOLS; ++m) mstart[m] = K_N_ATOMS;
  }
}

__global__ void k_scatter(const int* __restrict__ esrc, const int* __restrict__ edst,
                          int* __restrict__ cur, int2* __restrict__ ep) {
  int t = blockIdx.x * 256 + threadIdx.x;
  if (t < K_N_EDGES) {
    int s = esrc[t];
    int p = atomicAdd(&cur[s], 1);
    ep[p] = make_int2(s, edst[t]);
  }
}

// ---- step-0 F/G GEMM reading f32 states; F,G separate arrays ----
__global__ __launch_bounds__(256, 4) void fg_gemm0(
    const float* __restrict__ st_in, unsigned short* __restrict__ Fb,
    unsigned short* __restrict__ Gb,
    const unsigned short* __restrict__ wfg, const float* __restrict__ bin) {
  const int tid = threadIdx.x;
  const int wave = tid >> 6, lane = tid & 63, lo = lane & 15, h = lane >> 4;
  const int atom0 = (blockIdx.x * 4 + wave) * 16;
  const int a = atom0 + lo;
  const int ac = (a < K_N_ATOMS) ? a : (K_N_ATOMS - 1);

  const float* row = st_in + (size_t)ac * 64 + h * 8;
  bf16x8 b0 = pack8(*(const float4*)row, *(const float4*)(row + 4));
  bf16x8 b1 = pack8(*(const float4*)(row + 32), *(const float4*)(row + 36));

#pragma unroll
  for (int jt = 0; jt < 16; ++jt) {
    f32x4 acc;
    if (jt < 8) acc = *(const f32x4*)(bin + jt * 16 + h * 4);
    else { acc[0] = 0.f; acc[1] = 0.f; acc[2] = 0.f; acc[3] = 0.f; }
    bf16x8 a0 = *(const bf16x8*)(wfg + ((jt * 2 + 0) * 64 + lane) * 8);
    bf16x8 a1 = *(const bf16x8*)(wfg + ((jt * 2 + 1) * 64 + lane) * 8);
    acc = __builtin_amdgcn_mfma_f32_16x16x32_bf16(a0, b0, acc, 0, 0, 0);
    acc = __builtin_amdgcn_mfma_f32_16x16x32_bf16(a1, b1, acc, 0, 0, 0);
    if (a < K_N_ATOMS) {
      unsigned short* dst = (jt < 8) ? (Fb + (size_t)a * 128 + jt * 16 + h * 4)
                                     : (Gb + (size_t)a * 128 + (jt - 8) * 16 + h * 4);
      *(uint2*)dst = make_uint2(pk2(acc[0], acc[1]), pk2(acc[2], acc[3]));
    }
  }
}

// ---- fused message-aggregation + F/G GEMM (steps 1,2), 4-row unrolled ----
__global__ __launch_bounds__(256, 4) void agg_fg(
    const unsigned short* __restrict__ m_buf, const int* __restrict__ start,
    unsigned short* __restrict__ Fb, unsigned short* __restrict__ Gb,
    const unsigned short* __restrict__ wfg, const float* __restrict__ bin) {
  const int tid = threadIdx.x;
  const int wave = tid >> 6, lane = tid & 63, lo = lane & 15, h = lane >> 4;
  const int atom0 = (blockIdx.x * 4 + wave) * 16;
  const int a = atom0 + lo;

  int s = 0, e = 0;
  if (a < K_N_ATOMS) { s = start[a]; e = start[a + 1]; }

  float acc[16];
#pragma unroll
  for (int q = 0; q < 16; ++q) acc[q] = 0.f;
  int r = s;
  for (; r + 4 <= e; r += 4) {
    union { bf16x8 v; unsigned short w[8]; } u[8];
#pragma unroll
    for (int rr = 0; rr < 4; ++rr) {
      const unsigned short* p = m_buf + (size_t)(r + rr) * 64 + h * 8;
      u[2 * rr].v = *(const bf16x8*)(p);
      u[2 * rr + 1].v = *(const bf16x8*)(p + 32);
    }
#pragma unroll
    for (int q = 0; q < 8; ++q) {
      acc[q] += (bf2f(u[0].w[q]) + bf2f(u[2].w[q])) + (bf2f(u[4].w[q]) + bf2f(u[6].w[q]));
      acc[8 + q] += (bf2f(u[1].w[q]) + bf2f(u[3].w[q])) + (bf2f(u[5].w[q]) + bf2f(u[7].w[q]));
    }
  }
  for (; r < e; ++r) {
    const unsigned short* p = m_buf + (size_t)r * 64 + h * 8;
    union { bf16x8 v; unsigned short w[8]; } u0, u1;
    u0.v = *(const bf16x8*)(p);
    u1.v = *(const bf16x8*)(p + 32);
#pragma unroll
    for (int q = 0; q < 8; ++q) { acc[q] += bf2f(u0.w[q]); acc[8 + q] += bf2f(u1.w[q]); }
  }
  union { bf16x8 v; unsigned u[4]; } c0, c1;
#pragma unroll
  for (int q = 0; q < 4; ++q) {
    c0.u[q] = pk2(acc[2 * q], acc[2 * q + 1]);
    c1.u[q] = pk2(acc[8 + 2 * q], acc[8 + 2 * q + 1]);
  }
  bf16x8 b0 = c0.v, b1 = c1.v;

#pragma unroll
  for (int jt = 0; jt < 16; ++jt) {
    f32x4 d;
    if (jt < 8) d = *(const f32x4*)(bin + jt * 16 + h * 4);
    else { d[0] = 0.f; d[1] = 0.f; d[2] = 0.f; d[3] = 0.f; }
    bf16x8 a0 = *(const bf16x8*)(wfg + ((jt * 2 + 0) * 64 + lane) * 8);
    bf16x8 a1 = *(const bf16x8*)(wfg + ((jt * 2 + 1) * 64 + lane) * 8);
    d = __builtin_amdgcn_mfma_f32_16x16x32_bf16(a0, b0, d, 0, 0, 0);
    d = __builtin_amdgcn_mfma_f32_16x16x32_bf16(a1, b1, d, 0, 0, 0);
    if (a < K_N_ATOMS) {
      unsigned short* dst = (jt < 8) ? (Fb + (size_t)a * 128 + jt * 16 + h * 4)
                                     : (Gb + (size_t)a * 128 + (jt - 8) * 16 + h * 4);
      *(uint2*)dst = make_uint2(pk2(d[0], d[1]), pk2(d[2], d[3]));
    }
  }
}

// ---- edge MLP: w2 in LDS (32KB -> 5 blocks/CU), w3 from global (L2-hot) ----
// Issue order (vmcnt in-order): ep loads, staging loads, gathers LAST.
__device__ __forceinline__ void layer128_2(const unsigned short* wf,
                                           const float* __restrict__ bias,
                                           bf16x8 (&bfr)[2][4], unsigned (&p)[2][8][2],
                                           int lane, int h) {
#pragma unroll
  for (int jt = 0; jt < 8; ++jt) {
    f32x4 bv = *(const f32x4*)(bias + jt * 16 + h * 4);
    f32x4 a0 = bv, a1 = bv;
#pragma unroll
    for (int ks = 0; ks < 4; ++ks) {
      bf16x8 a = *(const bf16x8*)(wf + ((jt * 4 + ks) * 64 + lane) * 8);
      a0 = __builtin_amdgcn_mfma_f32_16x16x32_bf16(a, bfr[0][ks], a0, 0, 0, 0);
      a1 = __builtin_amdgcn_mfma_f32_16x16x32_bf16(a, bfr[1][ks], a1, 0, 0, 0);
    }
    p[0][jt][0] = pk2(relu(a0[0]), relu(a0[1])); p[0][jt][1] = pk2(relu(a0[2]), relu(a0[3]));
    p[1][jt][0] = pk2(relu(a1[0]), relu(a1[1])); p[1][jt][1] = pk2(relu(a1[2]), relu(a1[3]));
  }
}

__device__ __forceinline__ void transpose_p2(const unsigned (&p)[2][8][2], bf16x8 (&bfr)[2][4],
                                             int lo, int h) {
  const int hsel = (h & 1) * 2;
#pragma unroll
  for (int et = 0; et < 2; ++et) {
#pragma unroll
    for (int ks = 0; ks < 4; ++ks) {
      union { unsigned u[4]; bf16x8 v; } cv;
#pragma unroll
      for (int w = 0; w < 4; ++w) {
        int srcLane = lo + 16 * (hsel + (w >> 1));
        unsigned d0 = (unsigned)__shfl((int)p[et][2 * ks][w & 1], srcLane, 64);
        unsigned d1 = (unsigned)__shfl((int)p[et][2 * ks + 1][w & 1], srcLane, 64);
        cv.u[w] = (h < 2) ? d0 : d1;
      }
      bfr[et][ks] = cv.v;
    }
  }
}

__global__ __launch_bounds__(512, 4) void edge_msg4(
    const unsigned short* __restrict__ Fb, const unsigned short* __restrict__ Gb,
    unsigned short* __restrict__ m_buf,
    const int2* __restrict__ ep, const unsigned short* __restrict__ wf23,
    const float* __restrict__ b2, const float* __restrict__ b3) {
  __shared__ unsigned short wl[16384];  // w2 only, 32 KB -> 5 blocks/CU
  const int tid = threadIdx.x;
  const int wave = tid >> 6, lane = tid & 63, lo = lane & 15, h = lane >> 4;
  const int ebase = blockIdx.x * 256 + wave * 32;

  // (0) edge-pair loads (oldest)
  int srcs[2], dsts[2];
  unsigned vmask = 0;
#pragma unroll
  for (int et = 0; et < 2; ++et) {
    int e = ebase + et * 16 + lo;
    if (e < K_N_EDGES) vmask |= 1u << et;
    int ec = (e < K_N_EDGES) ? e : (K_N_EDGES - 1);
    int2 pr = ep[ec];
    srcs[et] = pr.x;
    dsts[et] = pr.y;
  }
  __builtin_amdgcn_sched_barrier(0);

  // (1) w2 staging loads -> registers (older than gathers)
  bf16x8 wreg[4];
#pragma unroll
  for (int i = 0; i < 4; ++i)
    wreg[i] = ((const bf16x8*)wf23)[i * 512 + tid];
  __builtin_amdgcn_sched_barrier(0);

  // (2) F/G gather loads (youngest — stay in flight across the ds_writes)
  bf16x8 fr[2][4], gr[2][4];
#pragma unroll
  for (int et = 0; et < 2; ++et) {
    const unsigned short* pf = Fb + (size_t)srcs[et] * 128 + h * 8;
    const unsigned short* pg = Gb + (size_t)dsts[et] * 128 + h * 8;
#pragma unroll
    for (int ks = 0; ks < 4; ++ks) {
      fr[et][ks] = *(const bf16x8*)(pf + ks * 32);
      gr[et][ks] = *(const bf16x8*)(pg + ks * 32);
    }
  }
  __builtin_amdgcn_sched_barrier(0);

  // (3) ds_write staged w2 (waits vmcnt for staging only), (4) barrier
#pragma unroll
  for (int i = 0; i < 4; ++i)
    ((bf16x8*)wl)[i * 512 + tid] = wreg[i];
  __syncthreads();

  // (5) h1 B-frags: relu(F[src] + G[dst]) — gather waitcnt lands here
  bf16x8 bfr[2][4];
#pragma unroll
  for (int et = 0; et < 2; ++et)
#pragma unroll
    for (int ks = 0; ks < 4; ++ks)
      bfr[et][ks] = addrelu8(fr[et][ks], gr[et][ks]);

  unsigned p[2][8][2];
  layer128_2(wl, b2, bfr, p, lane, h);
  transpose_p2(p, bfr, lo, h);

  // layer 3: w3 A-frags straight from global (L2-hot, 16 KB working set)
  const unsigned short* w3 = wf23 + 16384;
#pragma unroll
  for (int jt = 0; jt < 4; ++jt) {
    f32x4 bv = *(const f32x4*)(b3 + jt * 16 + h * 4);
    f32x4 a0 = bv, a1 = bv;
#pragma unroll
    for (int ks = 0; ks < 4; ++ks) {
      bf16x8 a = *(const bf16x8*)(w3 + ((jt * 4 + ks) * 64 + lane) * 8);
      a0 = __builtin_amdgcn_mfma_f32_16x16x32_bf16(a, bfr[0][ks], a0, 0, 0, 0);
      a1 = __builtin_amdgcn_mfma_f32_16x16x32_bf16(a, bfr[1][ks], a1, 0, 0, 0);
    }
    f32x4 accs[2] = {a0, a1};
#pragma unroll
    for (int et = 0; et < 2; ++et) {
      if (vmask & (1u << et)) {
        int e = ebase + et * 16 + lo;
        *(uint2*)(m_buf + (size_t)e * 64 + jt * 16 + h * 4) =
            make_uint2(pk2(relu(accs[et][0]), relu(accs[et][1])),
                       pk2(relu(accs[et][2]), relu(accs[et][3])));
      }
    }
  }
}

// ---- direct per-molecule message sum: one wave per molecule ----
__global__ __launch_bounds__(256) void mol_msum(
    const unsigned short* __restrict__ m_buf, const int* __restrict__ start,
    const int* __restrict__ mstart, float* __restrict__ mol) {
  int wv = (blockIdx.x * 256 + threadIdx.x) >> 6;
  int lane = threadIdx.x & 63;
  if (wv >= K_N_MOLS) return;
  int sub = lane & 7, rg = lane >> 3;
  int s = start[mstart[wv]], e = start[mstart[wv + 1]];
  float acc[8] = {0.f, 0.f, 0.f, 0.f, 0.f, 0.f, 0.f, 0.f};
  for (int r = s + rg; r < e; r += 8) {
    union { bf16x8 v; unsigned short w[8]; } u;
    u.v = *(const bf16x8*)(m_buf + (size_t)r * 64 + sub * 8);
#pragma unroll
    for (int q = 0; q < 8; ++q) acc[q] += bf2f(u.w[q]);
  }
#pragma unroll
  for (int off = 8; off <= 32; off <<= 1) {
#pragma unroll
    for (int q = 0; q < 8; ++q) acc[q] += __shfl_xor(acc[q], off, 64);
  }
  if (rg == 0) {
    float* p = mol + (size_t)wv * 64 + sub * 8;
    *(float4*)(p) = make_float4(acc[0], acc[1], acc[2], acc[3]);
    *(float4*)(p + 4) = make_float4(acc[4], acc[5], acc[6], acc[7]);
  }
}

// ---- fused readout MLP: 4 mols/block, float4-vectorized LDS reads ----
__global__ __launch_bounds__(256) void ro_fused(
    const float* __restrict__ mol, const float* __restrict__ Win,
    const float* __restrict__ bin, const float* __restrict__ Wh,
    const float* __restrict__ bh, const float* __restrict__ Wout,
    const float* __restrict__ bout, float* __restrict__ out) {
  __shared__ float a[4][64];
  __shared__ float h0[4][260];   // 1040B row stride: 16B-aligned
  __shared__ float h1[4][260];
  __shared__ float red[4][256];
  int m0 = blockIdx.x * 4;
  int t = threadIdx.x;
  if (t < 256) {
    int m = t >> 6, k = t & 63;
    a[m][k] = mol[(size_t)(m0 + m) * 64 + k];
  }
  __syncthreads();
  const int j = t;
  float acc[4];
  // L1: 64 -> 256
  {
    float b = bin[j];
#pragma unroll
    for (int m = 0; m < 4; ++m) acc[m] = b;
    for (int k = 0; k < 64; k += 4) {
      float w0 = Win[k * 256 + j], w1 = Win[(k + 1) * 256 + j];
      float w2 = Win[(k + 2) * 256 + j], w3 = Win[(k + 3) * 256 + j];
#pragma unroll
      for (int m = 0; m < 4; ++m) {
        float4 hv = *(const float4*)&a[m][k];
        acc[m] += hv.x * w0 + hv.y * w1 + hv.z * w2 + hv.w * w3;
      }
    }
#pragma unroll
    for (int m = 0; m < 4; ++m) h0[m][j] = relu(acc[m]);
  }
  __syncthreads();
  // L2: 256 -> 256 (Wh[0])
  {
    float b = bh[j];
#pragma unroll
    for (int m = 0; m < 4; ++m) acc[m] = b;
    for (int k = 0; k < 256; k += 4) {
      float w0 = Wh[k * 256 + j], w1 = Wh[(k + 1) * 256 + j];
      float w2 = Wh[(k + 2) * 256 + j], w3 = Wh[(k + 3) * 256 + j];
#pragma unroll
      for (int m = 0; m < 4; ++m) {
        float4 hv = *(const float4*)&h0[m][k];
        acc[m] += hv.x * w0 + hv.y * w1 + hv.z * w2 + hv.w * w3;
      }
    }
#pragma unroll
    for (int m = 0; m < 4; ++m) h1[m][j] = relu(acc[m]);
  }
  __syncthreads();
  // L3: 256 -> 256 (Wh[1])
  {
    float b = bh[256 + j];
#pragma unroll
    for (int m = 0; m < 4; ++m) acc[m] = b;
    for (int k = 0; k < 256; k += 4) {
      float w0 = Wh[65536 + k * 256 + j], w1 = Wh[65536 + (k + 1) * 256 + j];
      float w2 = Wh[65536 + (k + 2) * 256 + j], w3 = Wh[65536 + (k + 3) * 256 + j];
#pragma unroll
      for (int m = 0; m < 4; ++m) {
        float4 hv = *(const float4*)&h1[m][k];
        acc[m] += hv.x * w0 + hv.y * w1 + hv.z * w2 + hv.w * w3;
      }
    }
#pragma unroll
    for (int m = 0; m < 4; ++m) h0[m][j] = relu(acc[m]);
  }
  __syncthreads();
  // L4: 256 -> 1
  {
    float wj = Wout[j];
#pragma unroll
    for (int m = 0; m < 4; ++m) red[m][j] = h0[m][j] * wj;
  }
  __syncthreads();
  for (int off = 128; off; off >>= 1) {
    if (j < off) {
#pragma unroll
      for (int m = 0; m < 4; ++m) red[m][j] += red[m][j + off];
    }
    __syncthreads();
  }
  if (j < 4) out[m0 + j] = red[j][0] + bout[0];
}

extern "C" void kernel_launch(void* const* d_in, const int* in_sizes, int n_in,
                              void* d_out, int out_size, void* d_ws, size_t ws_size,
                              hipStream_t stream) {
  const float* atom_states = (const float*)d_in[0];
  const int* esrc = (const int*)d_in[1];
  const int* edst = (const int*)d_in[2];
  const int* mol_ids = (const int*)d_in[3];
  const float* msWin = (const float*)d_in[4];
  const float* msbin = (const float*)d_in[5];
  const float* msWh = (const float*)d_in[6];
  const float* msbh = (const float*)d_in[7];
  const float* msWout = (const float*)d_in[8];
  const float* msbout = (const float*)d_in[9];
  const float* roWin = (const float*)d_in[10];
  const float* robin = (const float*)d_in[11];
  const float* roWh = (const float*)d_in[12];
  const float* robh = (const float*)d_in[13];
  const float* roWout = (const float*)d_in[14];
  const float* robout = (const float*)d_in[15];
  float* out = (float*)d_out;

  // workspace carve-out (~107 MB)
  unsigned short* m_buf = (unsigned short*)d_ws;            // 400000*64 bf16 = 51.2MB
  unsigned short* Fb = m_buf + (size_t)K_N_EDGES * 64;      // 100000*128 bf16 = 25.6MB
  unsigned short* Gb = Fb + (size_t)K_N_ATOMS * 128;        // 25.6MB
  int2* ep = (int2*)(Gb + (size_t)K_N_ATOMS * 128);         // 400000 int2
  int* cnt = (int*)(ep + K_N_EDGES);                        // 100000
  int* start = cnt + K_N_ATOMS;                             // 100001
  int* cur = start + K_N_ATOMS + 1;                         // 100000
  int* partial = cur + K_N_ATOMS;                           // 512
  unsigned short* wfb = (unsigned short*)(partial + 512);   // 3*40960 bf16
  int* mstart = (int*)(wfb + 3 * 40960);                    // 4001
  // mol repr aliases into Fb (free after last edge_msg4)
  float* mol = (float*)Fb;                                  // 4000*64 f32

  const int EG = (K_N_EDGES + 255) / 256;    // 1563
  const int AG = (K_N_ATOMS + 255) / 256;    // 391
  const int AG16 = (K_N_ATOMS + 63) / 64;    // 1563 (16 atoms/wave, 4 waves)

  prep_w<<<dim3(40, 3), 256, 0, stream>>>(msWin, msWh, msWout, wfb);

  // counting sort of edges by src -> CSR (+ mol bounds)
  hipMemsetAsync(cnt, 0, K_N_ATOMS * sizeof(int), stream);
  k_hist<<<EG, 256, 0, stream>>>(esrc, cnt);
  k_blocksum<<<AG, 256, 0, stream>>>(cnt, partial);
  k_scanpart2<<<1, 512, 0, stream>>>(partial, AG);
  k_scanfinal_bounds<<<AG, 256, 0, stream>>>(cnt, partial, start, cur, mol_ids, mstart);
  k_scatter<<<EG, 256, 0, stream>>>(esrc, edst, cur, ep);

  // step 0
  fg_gemm0<<<AG16, 256, 0, stream>>>(atom_states, Fb, Gb, wfb, msbin);
  edge_msg4<<<EG, 512, 0, stream>>>(Fb, Gb, m_buf, ep, wfb + 16384, msbh, msbout);
  // step 1
  agg_fg<<<AG16, 256, 0, stream>>>(m_buf, start, Fb, Gb, wfb + 40960, msbin + 128);
  edge_msg4<<<EG, 512, 0, stream>>>(Fb, Gb, m_buf, ep, wfb + 40960 + 16384,
                                    msbh + 128, msbout + 64);
  // step 2
  agg_fg<<<AG16, 256, 0, stream>>>(m_buf, start, Fb, Gb, wfb + 81920, msbin + 256);
  edge_msg4<<<EG, 512, 0, stream>>>(Fb, Gb, m_buf, ep, wfb + 81920 + 16384,
                                    msbh + 256, msbout + 128);

  // readout: mol repr = direct per-mol message sum, then fused MLP
  mol_msum<<<(K_N_MOLS * 64 + 255) / 256, 256, 0, stream>>>(m_buf, start, mstart, mol);
  ro_fused<<<K_N_MOLS / 4, 256, 0, stream>>>(mol, roWin, robin, roWh, robh,
                                             roWout, robout, out);
}

// Round 21
// 334.330 us; speedup vs baseline: 1.1038x; 1.1038x over previous
//
#include <hip/hip_runtime.h>
#include <hip/hip_bf16.h>

#define K_N_ATOMS 100000
#define K_N_EDGES 400000
#define K_N_MOLS  4000

typedef __attribute__((ext_vector_type(8))) short bf16x8;
typedef __attribute__((ext_vector_type(4))) float f32x4;

__device__ __forceinline__ unsigned short f2bf(float x) {
  union { __hip_bfloat16 b; unsigned short u; } c;
  c.b = __float2bfloat16(x);
  return c.u;
}

__device__ __forceinline__ float bf2f(unsigned short u) {
  union { float f; unsigned u; } c;
  c.u = ((unsigned)u) << 16;
  return c.f;
}

__device__ __forceinline__ unsigned pk2(float a, float b) {
  union { __hip_bfloat162 h; unsigned u; } c;
  c.h = __float22bfloat162_rn(make_float2(a, b));
  return c.u;
}

__device__ __forceinline__ bf16x8 pack8(float4 x, float4 y) {
  union { bf16x8 v; unsigned u[4]; } r;
  r.u[0] = pk2(x.x, x.y); r.u[1] = pk2(x.z, x.w);
  r.u[2] = pk2(y.x, y.y); r.u[3] = pk2(y.z, y.w);
  return r.v;
}

__device__ __forceinline__ float relu(float x) { return fmaxf(x, 0.f); }

// h1 fragment: relu(F + G) elementwise on bf16x8
__device__ __forceinline__ bf16x8 addrelu8(bf16x8 a, bf16x8 b) {
  union { bf16x8 v; unsigned short s[8]; } ua, ub;
  ua.v = a; ub.v = b;
  union { bf16x8 v; unsigned u[4]; } r;
#pragma unroll
  for (int q = 0; q < 4; ++q) {
    float x0 = relu(bf2f(ua.s[2 * q]) + bf2f(ub.s[2 * q]));
    float x1 = relu(bf2f(ua.s[2 * q + 1]) + bf2f(ub.s[2 * q + 1]));
    r.u[q] = pk2(x0, x1);
  }
  return r.v;
}

// ---- weight prep ----
// per step s, layout in wf + s*40960 (shorts):
//   [0,16384)      wfg: A-frags of W' [64 x 256] (W_top|W_bot of Win), jt 0..15, ks 0..1
//   [16384,32768)  w2:  A-frags of Wh [128 x 128], ((jt*4+ks)*64+ln)*8+i
//   [32768,40960)  w3:  A-frags of Wout [128 x 64]
__global__ void prep_w(const float* __restrict__ Win, const float* __restrict__ Wh,
                       const float* __restrict__ Wout, unsigned short* __restrict__ wf) {
  int s = blockIdx.y;
  int flat = (blockIdx.x * 256 + threadIdx.x) * 4;  // 40960 elems, grid.x = 40
  if (flat < 16384) {
    const float* W = Win + s * 16384;
    unsigned short* dst = wf + s * 40960;
    int k = flat >> 7, j = flat & 127;
    float4 w4 = *(const float4*)(W + flat);
    float wv[4] = {w4.x, w4.y, w4.z, w4.w};
#pragma unroll
    for (int c = 0; c < 4; ++c) {
      int jj = j + c, kk = k;
      if (k >= 64) { kk = k - 64; jj += 128; }
      int jt = jj >> 4, ks = kk >> 5, ln = (jj & 15) + 16 * ((kk >> 3) & 3), i = kk & 7;
      dst[((jt * 2 + ks) * 64 + ln) * 8 + i] = f2bf(wv[c]);
    }
  } else if (flat < 32768) {
    const float* W = Wh + s * 16384;
    unsigned short* dst = wf + s * 40960 + 16384;
    int local = flat - 16384;
    int k = local >> 7, j = local & 127;
    float4 w4 = *(const float4*)(W + local);
    float wv[4] = {w4.x, w4.y, w4.z, w4.w};
    int ks = k >> 5, kr = (k >> 3) & 3, i = k & 7;
#pragma unroll
    for (int c = 0; c < 4; ++c) {
      int jj = j + c;
      int jt = jj >> 4, ln = (jj & 15) + 16 * kr;
      dst[((jt * 4 + ks) * 64 + ln) * 8 + i] = f2bf(wv[c]);
    }
  } else {
    const float* W = Wout + s * 8192;
    unsigned short* dst = wf + s * 40960 + 32768;
    int local = flat - 32768;
    int k = local >> 6, j = local & 63;
    float4 w4 = *(const float4*)(W + local);
    float wv[4] = {w4.x, w4.y, w4.z, w4.w};
    int ks = k >> 5, kr = (k >> 3) & 3, i = k & 7;
#pragma unroll
    for (int c = 0; c < 4; ++c) {
      int jj = j + c;
      int jt = jj >> 4, ln = (jj & 15) + 16 * kr;
      dst[((jt * 4 + ks) * 64 + ln) * 8 + i] = f2bf(wv[c]);
    }
  }
}

// ---- counting sort of edges by src ----
__global__ void k_hist(const int* __restrict__ esrc, int* __restrict__ cnt) {
  int t = blockIdx.x * 256 + threadIdx.x;
  if (t < K_N_EDGES) atomicAdd(&cnt[esrc[t]], 1);
}

__global__ void k_blocksum(const int* __restrict__ cnt, int* __restrict__ partial) {
  __shared__ int red[256];
  int i = blockIdx.x * 256 + threadIdx.x;
  red[threadIdx.x] = (i < K_N_ATOMS) ? cnt[i] : 0;
  __syncthreads();
  for (int off = 128; off; off >>= 1) {
    if (threadIdx.x < off) red[threadIdx.x] += red[threadIdx.x + off];
    __syncthreads();
  }
  if (!threadIdx.x) partial[blockIdx.x] = red[0];
}

__global__ void k_scanpart2(int* __restrict__ partial, int nb) {
  __shared__ int sh[512];
  int tid = threadIdx.x;
  int v = (tid < nb) ? partial[tid] : 0;
  sh[tid] = v;
  __syncthreads();
  for (int off = 1; off < 512; off <<= 1) {
    int t = (tid >= off) ? sh[tid - off] : 0;
    __syncthreads();
    sh[tid] += t;
    __syncthreads();
  }
  if (tid < nb) partial[tid] = sh[tid] - v;  // exclusive prefix
}

// scanfinal + mol_bounds merged (same grid shape)
__global__ void k_scanfinal_bounds(const int* __restrict__ cnt, const int* __restrict__ poffs,
                                   int* __restrict__ start, int* __restrict__ cur,
                                   const int* __restrict__ mol_ids, int* __restrict__ mstart) {
  __shared__ int sh[256];
  int tid = threadIdx.x;
  int i = blockIdx.x * 256 + tid;
  int v = (i < K_N_ATOMS) ? cnt[i] : 0;
  sh[tid] = v;
  __syncthreads();
  for (int off = 1; off < 256; off <<= 1) {
    int t = (tid >= off) ? sh[tid - off] : 0;
    __syncthreads();
    sh[tid] += t;
    __syncthreads();
  }
  int ex = sh[tid] - v + poffs[blockIdx.x];
  if (i < K_N_ATOMS) { start[i] = ex; cur[i] = ex; }
  if (i == K_N_ATOMS - 1) start[K_N_ATOMS] = ex + v;

  if (i < K_N_ATOMS) {
    int id = mol_ids[i];
    int prev = (i == 0) ? -1 : mol_ids[i - 1];
    for (int m = prev + 1; m <= id; ++m) mstart[m] = i;
    if (i == K_N_ATOMS - 1)
      for (int m = id + 1; m <= K_N_MOLS; ++m) mstart[m] = K_N_ATOMS;
  }
}

__global__ void k_scatter(const int* __restrict__ esrc, const int* __restrict__ edst,
                          int* __restrict__ cur, int2* __restrict__ ep) {
  int t = blockIdx.x * 256 + threadIdx.x;
  if (t < K_N_EDGES) {
    int s = esrc[t];
    int p = atomicAdd(&cur[s], 1);
    ep[p] = make_int2(s, edst[t]);
  }
}

// ---- step-0 F/G GEMM reading f32 states; F,G separate arrays ----
__global__ __launch_bounds__(256, 4) void fg_gemm0(
    const float* __restrict__ st_in, unsigned short* __restrict__ Fb,
    unsigned short* __restrict__ Gb,
    const unsigned short* __restrict__ wfg, const float* __restrict__ bin) {
  const int tid = threadIdx.x;
  const int wave = tid >> 6, lane = tid & 63, lo = lane & 15, h = lane >> 4;
  const int atom0 = (blockIdx.x * 4 + wave) * 16;
  const int a = atom0 + lo;
  const int ac = (a < K_N_ATOMS) ? a : (K_N_ATOMS - 1);

  const float* row = st_in + (size_t)ac * 64 + h * 8;
  bf16x8 b0 = pack8(*(const float4*)row, *(const float4*)(row + 4));
  bf16x8 b1 = pack8(*(const float4*)(row + 32), *(const float4*)(row + 36));

#pragma unroll
  for (int jt = 0; jt < 16; ++jt) {
    f32x4 acc;
    if (jt < 8) acc = *(const f32x4*)(bin + jt * 16 + h * 4);
    else { acc[0] = 0.f; acc[1] = 0.f; acc[2] = 0.f; acc[3] = 0.f; }
    bf16x8 a0 = *(const bf16x8*)(wfg + ((jt * 2 + 0) * 64 + lane) * 8);
    bf16x8 a1 = *(const bf16x8*)(wfg + ((jt * 2 + 1) * 64 + lane) * 8);
    acc = __builtin_amdgcn_mfma_f32_16x16x32_bf16(a0, b0, acc, 0, 0, 0);
    acc = __builtin_amdgcn_mfma_f32_16x16x32_bf16(a1, b1, acc, 0, 0, 0);
    if (a < K_N_ATOMS) {
      unsigned short* dst = (jt < 8) ? (Fb + (size_t)a * 128 + jt * 16 + h * 4)
                                     : (Gb + (size_t)a * 128 + (jt - 8) * 16 + h * 4);
      *(uint2*)dst = make_uint2(pk2(acc[0], acc[1]), pk2(acc[2], acc[3]));
    }
  }
}

// ---- fused message-aggregation + F/G GEMM (steps 1,2), 4-row unrolled ----
__global__ __launch_bounds__(256, 4) void agg_fg(
    const unsigned short* __restrict__ m_buf, const int* __restrict__ start,
    unsigned short* __restrict__ Fb, unsigned short* __restrict__ Gb,
    const unsigned short* __restrict__ wfg, const float* __restrict__ bin) {
  const int tid = threadIdx.x;
  const int wave = tid >> 6, lane = tid & 63, lo = lane & 15, h = lane >> 4;
  const int atom0 = (blockIdx.x * 4 + wave) * 16;
  const int a = atom0 + lo;

  int s = 0, e = 0;
  if (a < K_N_ATOMS) { s = start[a]; e = start[a + 1]; }

  float acc[16];
#pragma unroll
  for (int q = 0; q < 16; ++q) acc[q] = 0.f;
  int r = s;
  for (; r + 4 <= e; r += 4) {
    union { bf16x8 v; unsigned short w[8]; } u[8];
#pragma unroll
    for (int rr = 0; rr < 4; ++rr) {
      const unsigned short* p = m_buf + (size_t)(r + rr) * 64 + h * 8;
      u[2 * rr].v = *(const bf16x8*)(p);
      u[2 * rr + 1].v = *(const bf16x8*)(p + 32);
    }
#pragma unroll
    for (int q = 0; q < 8; ++q) {
      acc[q] += (bf2f(u[0].w[q]) + bf2f(u[2].w[q])) + (bf2f(u[4].w[q]) + bf2f(u[6].w[q]));
      acc[8 + q] += (bf2f(u[1].w[q]) + bf2f(u[3].w[q])) + (bf2f(u[5].w[q]) + bf2f(u[7].w[q]));
    }
  }
  for (; r < e; ++r) {
    const unsigned short* p = m_buf + (size_t)r * 64 + h * 8;
    union { bf16x8 v; unsigned short w[8]; } u0, u1;
    u0.v = *(const bf16x8*)(p);
    u1.v = *(const bf16x8*)(p + 32);
#pragma unroll
    for (int q = 0; q < 8; ++q) { acc[q] += bf2f(u0.w[q]); acc[8 + q] += bf2f(u1.w[q]); }
  }
  union { bf16x8 v; unsigned u[4]; } c0, c1;
#pragma unroll
  for (int q = 0; q < 4; ++q) {
    c0.u[q] = pk2(acc[2 * q], acc[2 * q + 1]);
    c1.u[q] = pk2(acc[8 + 2 * q], acc[8 + 2 * q + 1]);
  }
  bf16x8 b0 = c0.v, b1 = c1.v;

#pragma unroll
  for (int jt = 0; jt < 16; ++jt) {
    f32x4 d;
    if (jt < 8) d = *(const f32x4*)(bin + jt * 16 + h * 4);
    else { d[0] = 0.f; d[1] = 0.f; d[2] = 0.f; d[3] = 0.f; }
    bf16x8 a0 = *(const bf16x8*)(wfg + ((jt * 2 + 0) * 64 + lane) * 8);
    bf16x8 a1 = *(const bf16x8*)(wfg + ((jt * 2 + 1) * 64 + lane) * 8);
    d = __builtin_amdgcn_mfma_f32_16x16x32_bf16(a0, b0, d, 0, 0, 0);
    d = __builtin_amdgcn_mfma_f32_16x16x32_bf16(a1, b1, d, 0, 0, 0);
    if (a < K_N_ATOMS) {
      unsigned short* dst = (jt < 8) ? (Fb + (size_t)a * 128 + jt * 16 + h * 4)
                                     : (Gb + (size_t)a * 128 + (jt - 8) * 16 + h * 4);
      *(uint2*)dst = make_uint2(pk2(d[0], d[1]), pk2(d[2], d[3]));
    }
  }
}

// ---- edge MLP: all weights in LDS (48KB), 512 threads, et=2 (r15 config) ----
// Issue order (vmcnt in-order): ep loads, staging loads, gathers LAST.
__device__ __forceinline__ void layer128_2(const unsigned short* wf,
                                           const float* __restrict__ bias,
                                           bf16x8 (&bfr)[2][4], unsigned (&p)[2][8][2],
                                           int lane, int h) {
#pragma unroll
  for (int jt = 0; jt < 8; ++jt) {
    f32x4 bv = *(const f32x4*)(bias + jt * 16 + h * 4);
    f32x4 a0 = bv, a1 = bv;
#pragma unroll
    for (int ks = 0; ks < 4; ++ks) {
      bf16x8 a = *(const bf16x8*)(wf + ((jt * 4 + ks) * 64 + lane) * 8);
      a0 = __builtin_amdgcn_mfma_f32_16x16x32_bf16(a, bfr[0][ks], a0, 0, 0, 0);
      a1 = __builtin_amdgcn_mfma_f32_16x16x32_bf16(a, bfr[1][ks], a1, 0, 0, 0);
    }
    p[0][jt][0] = pk2(relu(a0[0]), relu(a0[1])); p[0][jt][1] = pk2(relu(a0[2]), relu(a0[3]));
    p[1][jt][0] = pk2(relu(a1[0]), relu(a1[1])); p[1][jt][1] = pk2(relu(a1[2]), relu(a1[3]));
  }
}

__device__ __forceinline__ void transpose_p2(const unsigned (&p)[2][8][2], bf16x8 (&bfr)[2][4],
                                             int lo, int h) {
  const int hsel = (h & 1) * 2;
#pragma unroll
  for (int et = 0; et < 2; ++et) {
#pragma unroll
    for (int ks = 0; ks < 4; ++ks) {
      union { unsigned u[4]; bf16x8 v; } cv;
#pragma unroll
      for (int w = 0; w < 4; ++w) {
        int srcLane = lo + 16 * (hsel + (w >> 1));
        unsigned d0 = (unsigned)__shfl((int)p[et][2 * ks][w & 1], srcLane, 64);
        unsigned d1 = (unsigned)__shfl((int)p[et][2 * ks + 1][w & 1], srcLane, 64);
        cv.u[w] = (h < 2) ? d0 : d1;
      }
      bfr[et][ks] = cv.v;
    }
  }
}

__global__ __launch_bounds__(512, 4) void edge_msg4(
    const unsigned short* __restrict__ Fb, const unsigned short* __restrict__ Gb,
    unsigned short* __restrict__ m_buf,
    const int2* __restrict__ ep, const unsigned short* __restrict__ wf23,
    const float* __restrict__ b2, const float* __restrict__ b3) {
  __shared__ unsigned short wl[24576];  // w2 (16384) + w3 (8192) shorts, 48 KB
  const int tid = threadIdx.x;
  const int wave = tid >> 6, lane = tid & 63, lo = lane & 15, h = lane >> 4;
  const int ebase = blockIdx.x * 256 + wave * 32;

  // (0) edge-pair loads (oldest)
  int srcs[2], dsts[2];
  unsigned vmask = 0;
#pragma unroll
  for (int et = 0; et < 2; ++et) {
    int e = ebase + et * 16 + lo;
    if (e < K_N_EDGES) vmask |= 1u << et;
    int ec = (e < K_N_EDGES) ? e : (K_N_EDGES - 1);
    int2 pr = ep[ec];
    srcs[et] = pr.x;
    dsts[et] = pr.y;
  }
  __builtin_amdgcn_sched_barrier(0);

  // (1) weight staging loads -> registers (older than gathers)
  bf16x8 wreg[6];
#pragma unroll
  for (int i = 0; i < 6; ++i)
    wreg[i] = ((const bf16x8*)wf23)[i * 512 + tid];
  __builtin_amdgcn_sched_barrier(0);

  // (2) F/G gather loads (youngest — stay in flight across the ds_writes)
  bf16x8 fr[2][4], gr[2][4];
#pragma unroll
  for (int et = 0; et < 2; ++et) {
    const unsigned short* pf = Fb + (size_t)srcs[et] * 128 + h * 8;
    const unsigned short* pg = Gb + (size_t)dsts[et] * 128 + h * 8;
#pragma unroll
    for (int ks = 0; ks < 4; ++ks) {
      fr[et][ks] = *(const bf16x8*)(pf + ks * 32);
      gr[et][ks] = *(const bf16x8*)(pg + ks * 32);
    }
  }
  __builtin_amdgcn_sched_barrier(0);

  // (3) ds_write staged weights (waits vmcnt for staging only), (4) barrier
#pragma unroll
  for (int i = 0; i < 6; ++i)
    ((bf16x8*)wl)[i * 512 + tid] = wreg[i];
  __syncthreads();

  // (5) h1 B-frags: relu(F[src] + G[dst]) — gather waitcnt lands here
  bf16x8 bfr[2][4];
#pragma unroll
  for (int et = 0; et < 2; ++et)
#pragma unroll
    for (int ks = 0; ks < 4; ++ks)
      bfr[et][ks] = addrelu8(fr[et][ks], gr[et][ks]);

  unsigned p[2][8][2];
  layer128_2(wl, b2, bfr, p, lane, h);
  transpose_p2(p, bfr, lo, h);

  const unsigned short* w3 = wl + 16384;
#pragma unroll
  for (int jt = 0; jt < 4; ++jt) {
    f32x4 bv = *(const f32x4*)(b3 + jt * 16 + h * 4);
    f32x4 a0 = bv, a1 = bv;
#pragma unroll
    for (int ks = 0; ks < 4; ++ks) {
      bf16x8 a = *(const bf16x8*)(w3 + ((jt * 4 + ks) * 64 + lane) * 8);
      a0 = __builtin_amdgcn_mfma_f32_16x16x32_bf16(a, bfr[0][ks], a0, 0, 0, 0);
      a1 = __builtin_amdgcn_mfma_f32_16x16x32_bf16(a, bfr[1][ks], a1, 0, 0, 0);
    }
    f32x4 accs[2] = {a0, a1};
#pragma unroll
    for (int et = 0; et < 2; ++et) {
      if (vmask & (1u << et)) {
        int e = ebase + et * 16 + lo;
        *(uint2*)(m_buf + (size_t)e * 64 + jt * 16 + h * 4) =
            make_uint2(pk2(relu(accs[et][0]), relu(accs[et][1])),
                       pk2(relu(accs[et][2]), relu(accs[et][3])));
      }
    }
  }
}

// ---- direct per-molecule message sum: one wave per molecule ----
__global__ __launch_bounds__(256) void mol_msum(
    const unsigned short* __restrict__ m_buf, const int* __restrict__ start,
    const int* __restrict__ mstart, float* __restrict__ mol) {
  int wv = (blockIdx.x * 256 + threadIdx.x) >> 6;
  int lane = threadIdx.x & 63;
  if (wv >= K_N_MOLS) return;
  int sub = lane & 7, rg = lane >> 3;
  int s = start[mstart[wv]], e = start[mstart[wv + 1]];
  float acc[8] = {0.f, 0.f, 0.f, 0.f, 0.f, 0.f, 0.f, 0.f};
  for (int r = s + rg; r < e; r += 8) {
    union { bf16x8 v; unsigned short w[8]; } u;
    u.v = *(const bf16x8*)(m_buf + (size_t)r * 64 + sub * 8);
#pragma unroll
    for (int q = 0; q < 8; ++q) acc[q] += bf2f(u.w[q]);
  }
#pragma unroll
  for (int off = 8; off <= 32; off <<= 1) {
#pragma unroll
    for (int q = 0; q < 8; ++q) acc[q] += __shfl_xor(acc[q], off, 64);
  }
  if (rg == 0) {
    float* p = mol + (size_t)wv * 64 + sub * 8;
    *(float4*)(p) = make_float4(acc[0], acc[1], acc[2], acc[3]);
    *(float4*)(p + 4) = make_float4(acc[4], acc[5], acc[6], acc[7]);
  }
}

// ---- fused readout MLP: 4 mols/block, float4-vectorized LDS reads ----
__global__ __launch_bounds__(256) void ro_fused(
    const float* __restrict__ mol, const float* __restrict__ Win,
    const float* __restrict__ bin, const float* __restrict__ Wh,
    const float* __restrict__ bh, const float* __restrict__ Wout,
    const float* __restrict__ bout, float* __restrict__ out) {
  __shared__ float a[4][64];
  __shared__ float h0[4][260];   // 1040B row stride: 16B-aligned
  __shared__ float h1[4][260];
  __shared__ float red[4][256];
  int m0 = blockIdx.x * 4;
  int t = threadIdx.x;
  if (t < 256) {
    int m = t >> 6, k = t & 63;
    a[m][k] = mol[(size_t)(m0 + m) * 64 + k];
  }
  __syncthreads();
  const int j = t;
  float acc[4];
  // L1: 64 -> 256
  {
    float b = bin[j];
#pragma unroll
    for (int m = 0; m < 4; ++m) acc[m] = b;
    for (int k = 0; k < 64; k += 4) {
      float w0 = Win[k * 256 + j], w1 = Win[(k + 1) * 256 + j];
      float w2 = Win[(k + 2) * 256 + j], w3 = Win[(k + 3) * 256 + j];
#pragma unroll
      for (int m = 0; m < 4; ++m) {
        float4 hv = *(const float4*)&a[m][k];
        acc[m] += hv.x * w0 + hv.y * w1 + hv.z * w2 + hv.w * w3;
      }
    }
#pragma unroll
    for (int m = 0; m < 4; ++m) h0[m][j] = relu(acc[m]);
  }
  __syncthreads();
  // L2: 256 -> 256 (Wh[0])
  {
    float b = bh[j];
#pragma unroll
    for (int m = 0; m < 4; ++m) acc[m] = b;
    for (int k = 0; k < 256; k += 4) {
      float w0 = Wh[k * 256 + j], w1 = Wh[(k + 1) * 256 + j];
      float w2 = Wh[(k + 2) * 256 + j], w3 = Wh[(k + 3) * 256 + j];
#pragma unroll
      for (int m = 0; m < 4; ++m) {
        float4 hv = *(const float4*)&h0[m][k];
        acc[m] += hv.x * w0 + hv.y * w1 + hv.z * w2 + hv.w * w3;
      }
    }
#pragma unroll
    for (int m = 0; m < 4; ++m) h1[m][j] = relu(acc[m]);
  }
  __syncthreads();
  // L3: 256 -> 256 (Wh[1])
  {
    float b = bh[256 + j];
#pragma unroll
    for (int m = 0; m < 4; ++m) acc[m] = b;
    for (int k = 0; k < 256; k += 4) {
      float w0 = Wh[65536 + k * 256 + j], w1 = Wh[65536 + (k + 1) * 256 + j];
      float w2 = Wh[65536 + (k + 2) * 256 + j], w3 = Wh[65536 + (k + 3) * 256 + j];
#pragma unroll
      for (int m = 0; m < 4; ++m) {
        float4 hv = *(const float4*)&h1[m][k];
        acc[m] += hv.x * w0 + hv.y * w1 + hv.z * w2 + hv.w * w3;
      }
    }
#pragma unroll
    for (int m = 0; m < 4; ++m) h0[m][j] = relu(acc[m]);
  }
  __syncthreads();
  // L4: 256 -> 1
  {
    float wj = Wout[j];
#pragma unroll
    for (int m = 0; m < 4; ++m) red[m][j] = h0[m][j] * wj;
  }
  __syncthreads();
  for (int off = 128; off; off >>= 1) {
    if (j < off) {
#pragma unroll
      for (int m = 0; m < 4; ++m) red[m][j] += red[m][j + off];
    }
    __syncthreads();
  }
  if (j < 4) out[m0 + j] = red[j][0] + bout[0];
}

extern "C" void kernel_launch(void* const* d_in, const int* in_sizes, int n_in,
                              void* d_out, int out_size, void* d_ws, size_t ws_size,
                              hipStream_t stream) {
  const float* atom_states = (const float*)d_in[0];
  const int* esrc = (const int*)d_in[1];
  const int* edst = (const int*)d_in[2];
  const int* mol_ids = (const int*)d_in[3];
  const float* msWin = (const float*)d_in[4];
  const float* msbin = (const float*)d_in[5];
  const float* msWh = (const float*)d_in[6];
  const float* msbh = (const float*)d_in[7];
  const float* msWout = (const float*)d_in[8];
  const float* msbout = (const float*)d_in[9];
  const float* roWin = (const float*)d_in[10];
  const float* robin = (const float*)d_in[11];
  const float* roWh = (const float*)d_in[12];
  const float* robh = (const float*)d_in[13];
  const float* roWout = (const float*)d_in[14];
  const float* robout = (const float*)d_in[15];
  float* out = (float*)d_out;

  // workspace carve-out (~107 MB)
  unsigned short* m_buf = (unsigned short*)d_ws;            // 400000*64 bf16 = 51.2MB
  unsigned short* Fb = m_buf + (size_t)K_N_EDGES * 64;      // 100000*128 bf16 = 25.6MB
  unsigned short* Gb = Fb + (size_t)K_N_ATOMS * 128;        // 25.6MB
  int2* ep = (int2*)(Gb + (size_t)K_N_ATOMS * 128);         // 400000 int2
  int* cnt = (int*)(ep + K_N_EDGES);                        // 100000
  int* start = cnt + K_N_ATOMS;                             // 100001
  int* cur = start + K_N_ATOMS + 1;                         // 100000
  int* partial = cur + K_N_ATOMS;                           // 512
  unsigned short* wfb = (unsigned short*)(partial + 512);   // 3*40960 bf16
  int* mstart = (int*)(wfb + 3 * 40960);                    // 4001
  // mol repr aliases into Fb (free after last edge_msg4)
  float* mol = (float*)Fb;                                  // 4000*64 f32

  const int EG = (K_N_EDGES + 255) / 256;    // 1563
  const int AG = (K_N_ATOMS + 255) / 256;    // 391
  const int AG16 = (K_N_ATOMS + 63) / 64;    // 1563 (16 atoms/wave, 4 waves)

  prep_w<<<dim3(40, 3), 256, 0, stream>>>(msWin, msWh, msWout, wfb);

  // counting sort of edges by src -> CSR (+ mol bounds)
  hipMemsetAsync(cnt, 0, K_N_ATOMS * sizeof(int), stream);
  k_hist<<<EG, 256, 0, stream>>>(esrc, cnt);
  k_blocksum<<<AG, 256, 0, stream>>>(cnt, partial);
  k_scanpart2<<<1, 512, 0, stream>>>(partial, AG);
  k_scanfinal_bounds<<<AG, 256, 0, stream>>>(cnt, partial, start, cur, mol_ids, mstart);
  k_scatter<<<EG, 256, 0, stream>>>(esrc, edst, cur, ep);

  // step 0
  fg_gemm0<<<AG16, 256, 0, stream>>>(atom_states, Fb, Gb, wfb, msbin);
  edge_msg4<<<EG, 512, 0, stream>>>(Fb, Gb, m_buf, ep, wfb + 16384, msbh, msbout);
  // step 1
  agg_fg<<<AG16, 256, 0, stream>>>(m_buf, start, Fb, Gb, wfb + 40960, msbin + 128);
  edge_msg4<<<EG, 512, 0, stream>>>(Fb, Gb, m_buf, ep, wfb + 40960 + 16384,
                                    msbh + 128, msbout + 64);
  // step 2
  agg_fg<<<AG16, 256, 0, stream>>>(m_buf, start, Fb, Gb, wfb + 81920, msbin + 256);
  edge_msg4<<<EG, 512, 0, stream>>>(Fb, Gb, m_buf, ep, wfb + 81920 + 16384,
                                    msbh + 256, msbout + 128);

  // readout: mol repr = direct per-mol message sum, then fused MLP
  mol_msum<<<(K_N_MOLS * 64 + 255) / 256, 256, 0, stream>>>(m_buf, start, mstart, mol);
  ro_fused<<<K_N_MOLS / 4, 256, 0, stream>>>(mol, roWin, robin, roWh, robh,
                                             roWout, robout, out);
}